// Round 1
// baseline (383.961 us; speedup 1.0000x reference)
//
#include <hip/hip_runtime.h>
#include <hip/hip_bf16.h>

#define N_NEURON 1024
#define N_PEPTIDE 16
#define N_GENES 1
#define BATCH 2048
#define SQ 32
#define DT_STEP (1.0f/120.0f)
#define S_STRIDE (N_NEURON + N_GENES + N_NEURON + N_NEURON*N_PEPTIDE) // 18433

typedef __attribute__((ext_vector_type(8))) short short8;
typedef __attribute__((ext_vector_type(4))) float floatx4;

// -------------------------------------------------------------------------
// Kernel 1: synapse (K x N fp32, row-major) -> synT (N x K bf16, row-major)
// LDS 32x33 tile transpose, coalesced both sides.
// -------------------------------------------------------------------------
__global__ __launch_bounds__(256) void synT_cast(const float* __restrict__ syn,
                                                 __hip_bfloat16* __restrict__ synT) {
    __shared__ float tile[32][33];
    const int n0 = blockIdx.x * 32;
    const int k0 = blockIdx.y * 32;
    const int tx = threadIdx.x & 31;
    const int ty = threadIdx.x >> 5; // 0..7
    #pragma unroll
    for (int i = 0; i < 4; ++i)
        tile[ty + i*8][tx] = syn[(long)(k0 + ty + i*8) * N_NEURON + n0 + tx];
    __syncthreads();
    #pragma unroll
    for (int i = 0; i < 4; ++i)
        synT[(long)(n0 + ty + i*8) * N_NEURON + k0 + tx] =
            __float2bfloat16(tile[tx][ty + i*8]);
}

// -------------------------------------------------------------------------
// Kernel 2: one block per batch row.
//   Phase 1: firing (fp32 to d_out, bf16 to ws), masked neuron to LDS,
//            ablate + pc2 copied into state_new.
//   Phase 2: peptide update (periodic 32x32 Laplacian), pep_sum reduction,
//            partial d_neuron c0 staged into state_new's neuron slot.
// -------------------------------------------------------------------------
__global__ __launch_bounds__(256) void fused_elem(
    const float* __restrict__ u,        // [B,1]
    const float* __restrict__ state,    // [B,S]
    const float* __restrict__ noise,    // [B,N]
    const float* __restrict__ D,        // [P]
    const float* __restrict__ prod_g,   // [P]
    const float* __restrict__ decay_g,  // [P]
    const float* __restrict__ pact_g,   // [P]
    const float* __restrict__ ndecay_g, // [1]
    const float* __restrict__ inL,      // [N]
    float* __restrict__ firing_out,     // [B,N]
    float* __restrict__ state_new,      // [B,S]
    __hip_bfloat16* __restrict__ fbf)   // [B,N]
{
    __shared__ float sf[N_NEURON]; // firing
    __shared__ float sn[N_NEURON]; // masked neuron
    const int b = blockIdx.x;
    const int tid = threadIdx.x;
    const long bS = (long)b * S_STRIDE;
    const float u_b = u[b];
    const float pc2 = state[bS + N_NEURON];
    const float ndecay = fabsf(ndecay_g[0]);

    // ---- phase 1: firing ----
    #pragma unroll
    for (int k = 0; k < 4; ++k) {
        const int n = tid + k * 256;
        const float ab = state[bS + n];
        const float nr = state[bS + N_NEURON + N_GENES + n];
        const float nm = nr * ab;
        float f = fmaxf(nr, 0.f) * ab;                      // relu(neuron)*ablate
        f = -(f + 0.01f) * log1pf(-noise[(long)b * N_NEURON + n]);
        f = fminf(fmaxf(f, 0.f), 10.f);
        firing_out[(long)b * N_NEURON + n] = f;
        fbf[(long)b * N_NEURON + n] = __float2bfloat16(f);
        state_new[bS + n] = ab;
        sf[n] = f;
        sn[n] = nm;
    }
    if (tid == 0) state_new[bS + N_NEURON] = pc2;
    __syncthreads();

    // ---- phase 2: peptide ----
    const int p = tid & 15;            // constant per thread (256 % 16 == 0)
    const float Dp      = fabsf(D[p]);
    const float prod_r  = fabsf(prod_g[p]);
    const float decay_r = fabsf(decay_g[p]);
    const float pact    = pact_g[p];
    const int g16 = tid >> 4;          // neuron subgroup 0..15

    const float* __restrict__ pep = state + bS + 2 * N_NEURON + N_GENES;
    float* __restrict__ pep_new = state_new + bS + 2 * N_NEURON + N_GENES;

    for (int it = 0; it < 64; ++it) {
        const int n = it * 16 + g16;
        const int si = n >> 5, sj = n & 31;
        const int iup = ((((si + 31) & 31) * 32 + sj) << 4) + p;
        const int idn = ((((si + 1) & 31) * 32 + sj) << 4) + p;
        const int ilf = ((si * 32 + ((sj + 31) & 31)) << 4) + p;
        const int irt = ((si * 32 + ((sj + 1) & 31)) << 4) + p;
        const int idx = (n << 4) + p;   // == it*256 + tid  (fully coalesced)
        const float c = pep[idx];
        const float lap = pep[iup] + pep[idn] + pep[ilf] + pep[irt] - 4.f * c;
        const float f = sf[n];
        pep_new[idx] = c + DT_STEP * (prod_r * f - decay_r * c + Dp * lap);

        float ps = c * pact;            // reduce over 16 lanes sharing n
        ps += __shfl_xor(ps, 1);
        ps += __shfl_xor(ps, 2);
        ps += __shfl_xor(ps, 4);
        ps += __shfl_xor(ps, 8);
        if (p == 0) {
            const float nm = sn[n];
            const float c0 = nm + DT_STEP * (ps * pc2 - nm * ndecay + inL[n] * u_b);
            state_new[bS + N_NEURON + N_GENES + n] = c0; // staged; GEMM epilogue finishes
        }
    }
}

// -------------------------------------------------------------------------
// Kernel 3: C[m][n] = firing[m][:] . synapse[:][n] via bf16 MFMA 16x16x32,
// fused epilogue: neuron_new = (c0 + DT*gemm) * ablate.
// Block = 256 threads = 4 waves, each wave a 32x32 tile -> block tile 64x64.
// A-frag: lane holds A[m0+ (lane&15)][k0 + (lane>>4)*8 + j], j=0..7
// B-frag: lane holds B[k0 + (lane>>4)*8 + j][n0 + (lane&15)] = synT[n][k..k+7]
// D: col = lane&15 (n), row = (lane>>4)*4 + reg (m)
// -------------------------------------------------------------------------
__global__ __launch_bounds__(256) void gemm_epi(
    const __hip_bfloat16* __restrict__ A,   // firing bf16 [B,K=1024]
    const __hip_bfloat16* __restrict__ BT,  // synT bf16 [N,K=1024]
    const float* __restrict__ state,        // for ablate
    float* __restrict__ state_new)
{
    const int tid = threadIdx.x;
    const int w = tid >> 6, lid = tid & 63;
    const int q = lid >> 4, l16 = lid & 15;
    const int m0 = blockIdx.x * 64 + (w & 1) * 32;
    const int n0 = blockIdx.y * 64 + (w >> 1) * 32;

    floatx4 acc[2][2] = {};
    for (int k0 = 0; k0 < 1024; k0 += 32) {
        short8 a[2], bfr[2];
        #pragma unroll
        for (int mi = 0; mi < 2; ++mi)
            a[mi] = *(const short8*)(A + (long)(m0 + mi * 16 + l16) * 1024 + k0 + q * 8);
        #pragma unroll
        for (int ni = 0; ni < 2; ++ni)
            bfr[ni] = *(const short8*)(BT + (long)(n0 + ni * 16 + l16) * 1024 + k0 + q * 8);
        #pragma unroll
        for (int mi = 0; mi < 2; ++mi)
            #pragma unroll
            for (int ni = 0; ni < 2; ++ni)
                acc[mi][ni] = __builtin_amdgcn_mfma_f32_16x16x32_bf16(
                    a[mi], bfr[ni], acc[mi][ni], 0, 0, 0);
    }

    #pragma unroll
    for (int mi = 0; mi < 2; ++mi)
    #pragma unroll
    for (int ni = 0; ni < 2; ++ni)
    #pragma unroll
    for (int r = 0; r < 4; ++r) {
        const int m = m0 + mi * 16 + q * 4 + r;
        const int n = n0 + ni * 16 + l16;
        const long sidx = (long)m * S_STRIDE;
        const float ab = state[sidx + n];
        const float c0 = state_new[sidx + N_NEURON + N_GENES + n];
        state_new[sidx + N_NEURON + N_GENES + n] = (c0 + DT_STEP * acc[mi][ni][r]) * ab;
    }
}

extern "C" void kernel_launch(void* const* d_in, const int* in_sizes, int n_in,
                              void* d_out, int out_size, void* d_ws, size_t ws_size,
                              hipStream_t stream) {
    const float* u      = (const float*)d_in[0];
    const float* state  = (const float*)d_in[1];
    const float* noise  = (const float*)d_in[2];
    const float* D      = (const float*)d_in[3];
    const float* prod   = (const float*)d_in[4];
    const float* decay  = (const float*)d_in[5];
    const float* pact   = (const float*)d_in[6];
    const float* syn    = (const float*)d_in[7];
    const float* ndec   = (const float*)d_in[8];
    const float* inL    = (const float*)d_in[9];

    float* firing = (float*)d_out;                          // [B,N]
    float* state_new = firing + (long)BATCH * N_NEURON;     // [B,S]

    __hip_bfloat16* fbf  = (__hip_bfloat16*)d_ws;           // 4 MB
    __hip_bfloat16* synT = fbf + (long)BATCH * N_NEURON;    // 2 MB

    hipLaunchKernelGGL(synT_cast, dim3(32, 32), dim3(256), 0, stream, syn, synT);
    hipLaunchKernelGGL(fused_elem, dim3(BATCH), dim3(256), 0, stream,
                       u, state, noise, D, prod, decay, pact, ndec, inL,
                       firing, state_new, fbf);
    hipLaunchKernelGGL(gemm_epi, dim3(32, 16), dim3(256), 0, stream,
                       fbf, synT, state, state_new);
}